// Round 8
// baseline (774.412 us; speedup 1.0000x reference)
//
#include <hip/hip_runtime.h>
#include <stdint.h>

#define M_DIM 512
#define K_DIM 8192
#define N_DIM 14336
#define NGRP  64      // K / 128 groups
#define BN    64      // N columns per GEMM workgroup
#define NTILE (N_DIM / BN)   // 224

typedef int   i32x4  __attribute__((ext_vector_type(4)));
typedef int   i32x16 __attribute__((ext_vector_type(16)));
typedef float f32x4  __attribute__((ext_vector_type(4)));

// ---------------- Kernel 1: per-row dynamic int8 quantization ----------------
// Writes qA in MFMA-fragment-native layout:
//   qA[((g*16 + tile)*4 + ks)*1024 + l31*32 + lhi*16 + b]
// where row = tile*32 + l31, k = g*128 + ks*32 + lhi*16 + b.
__global__ __launch_bounds__(256) void quant_rows(const float* __restrict__ A,
                                                  uint8_t* __restrict__ qA,
                                                  float* __restrict__ s1)
{
    const int row  = blockIdx.x;
    const int tid  = threadIdx.x;
    const int tile = row >> 5;
    const int l31  = row & 31;
    const f32x4* src = (const f32x4*)(A + (size_t)row * K_DIM) + tid;

    f32x4 v[8];
#pragma unroll
    for (int i = 0; i < 8; ++i) v[i] = src[i * 256];

    float m = 0.0f;
#pragma unroll
    for (int i = 0; i < 8; ++i)
        m = fmaxf(m, fmaxf(fmaxf(fabsf(v[i].x), fabsf(v[i].y)),
                           fmaxf(fabsf(v[i].z), fabsf(v[i].w))));
#pragma unroll
    for (int off = 32; off > 0; off >>= 1)
        m = fmaxf(m, __shfl_xor(m, off));

    __shared__ float wmax[4];
    if ((tid & 63) == 0) wmax[tid >> 6] = m;
    __syncthreads();
    const float gm = fmaxf(fmaxf(wmax[0], wmax[1]), fmaxf(wmax[2], wmax[3]));
    const float s = gm / 127.0f;   // exact fp32 division, matches reference
    if (tid == 0) s1[row] = s;

#pragma unroll
    for (int i = 0; i < 8; ++i) {
        const int k0  = 4 * (tid + 256 * i);
        const int g   = k0 >> 7;
        const int ks  = (k0 >> 5) & 3;
        const int lhi = (k0 >> 4) & 1;
        const int b   = k0 & 15;
        uint32_t p = 0;
#pragma unroll
        for (int j = 0; j < 4; ++j) {
            float q = rintf(v[i][j] / s);             // round-half-even = np.round
            q = fminf(fmaxf(q, -128.0f), 127.0f);
            p |= ((uint32_t)(uint8_t)(int8_t)(int)q) << (8 * j);
        }
        *(uint32_t*)(qA + (size_t)(g * 16 + tile) * 4096 + ks * 1024
                        + l31 * 32 + lhi * 16 + b) = p;
    }
}

// ---------------- Kernel 2: w4 int32 -> int8 GEMM-native repack (v2) --------
// Block covers 128 k-rows x 256 cols (1 KB contiguous per row -> DRAM page
// locality). Grid (56 nblk, 64 g), x fastest => concurrent blocks stream whole
// 57 KB k-rows collectively. Output tiles indexed [g][ntile] so writes are
// dispatch-contiguous too. Tile image (8 KB per (g,ntile)):
//   byte(col,k) = col*128 + (k ^ ((col&7)<<4)), value = w4[k][n]-8 as int8.
__global__ __launch_bounds__(256) void repack_w4(const int* __restrict__ w4,
                                                 uint8_t* __restrict__ w8)
{
    const int nblk = blockIdx.x;         // 0..55  (256-col slab)
    const int g    = blockIdx.y;         // 0..63
    const int t    = threadIdx.x;
    const int c4   = t & 63;             // col-quad within 256-col slab
    const int kr   = t >> 6;             // 0..3: 32-row k-chunk

    const int colg   = nblk * 256 + c4 * 4;           // global first col
    const int ntile  = colg >> 6;                     // output tile
    const int colt   = colg & 63;                     // col within tile
    uint8_t* dst = w8 + ((size_t)g * NTILE + ntile) * 8192;

#pragma unroll
    for (int sub = 0; sub < 4; ++sub) {
        const int krow = kr * 32 + sub * 8;           // k within group
        const int* src = w4 + (size_t)(g * 128 + krow) * N_DIM + colg;
        i32x4 r[8];
#pragma unroll
        for (int j = 0; j < 8; ++j)
            r[j] = *(const i32x4*)(src + (size_t)j * N_DIM);
#pragma unroll
        for (int c = 0; c < 4; ++c) {
            const int col = colt + c;
            uint32_t lo = ((uint32_t)(r[0][c] - 8) & 0xFFu)
                        | (((uint32_t)(r[1][c] - 8) & 0xFFu) << 8)
                        | (((uint32_t)(r[2][c] - 8) & 0xFFu) << 16)
                        | (((uint32_t)(r[3][c] - 8) & 0xFFu) << 24);
            uint32_t hi = ((uint32_t)(r[4][c] - 8) & 0xFFu)
                        | (((uint32_t)(r[5][c] - 8) & 0xFFu) << 8)
                        | (((uint32_t)(r[6][c] - 8) & 0xFFu) << 16)
                        | (((uint32_t)(r[7][c] - 8) & 0xFFu) << 24);
            // krow is 8-aligned; swz only touches bits 4..6 -> stays 8-aligned
            uint2 v = make_uint2(lo, hi);
            *(uint2*)&dst[col * 128 + (krow ^ ((col & 7) << 4))] = v;
        }
    }
}

// ---------------- Kernel 3: lean W8A8 GEMM ----------------
// BM=256 (4 waves), BN=64. 3 WGs/CU (LDS 48 KB, VGPR<=168). B staged by
// verbatim 8 KB DMA of the pre-swizzled w8 tile into a 4-deep LDS ring
// (depth-3 prefetch); qA fragments prefetched 1 group ahead into registers;
// s_group staged in LDS once. ONE barrier per group; counted vmcnt(12)
// keeps DMA(G+2..3) + qA(G+1) in flight across the barrier. XCD-aware block
// map co-locates an ntile's two m-halves on one XCD (w8 2nd read = L2 hit).

#define DMA_PK(BUF, G) do {                                                    \
    const uint8_t* s0_ = w8 + ((size_t)(G) * NTILE + ntile) * 8192             \
                         + wv * 1024 + lane * 16;                              \
    __builtin_amdgcn_global_load_lds(                                          \
        (const __attribute__((address_space(1))) void*)s0_,                    \
        (__attribute__((address_space(3))) void*)&pk[BUF][wv * 1024], 16, 0, 0);\
    __builtin_amdgcn_global_load_lds(                                          \
        (const __attribute__((address_space(1))) void*)(s0_ + 4096),           \
        (__attribute__((address_space(3))) void*)&pk[BUF][wv * 1024 + 4096],   \
        16, 0, 0);                                                             \
} while (0)

#define BODY(G, ACUR, ANXT) do {                                               \
    /* 1: prefetch A fragments for G+1 */                                      \
    { const int gn_ = ((G) + 1 < NGRP) ? (G) + 1 : NGRP - 1;                   \
      _Pragma("unroll")                                                        \
      for (int ms = 0; ms < 2; ++ms)                                           \
      _Pragma("unroll")                                                        \
      for (int ks = 0; ks < 4; ++ks)                                           \
          ANXT[ms][ks] = *(const i32x4*)(abase                                 \
              + (size_t)((gn_ * 16 + tile0 + ms) * 4 + ks) * 1024); }          \
    /* 2: issue DMA for G+3 */                                                 \
    { const int gd_ = ((G) + 3 < NGRP) ? (G) + 3 : NGRP - 1;                   \
      DMA_PK(((G) + 3) & 3, gd_); }                                            \
    /* 3: B fragments from pk[G&3] + group scales from LDS */                  \
    i32x4 bf_[2][4];                                                           \
    _Pragma("unroll")                                                          \
    for (int nt = 0; nt < 2; ++nt)                                             \
    _Pragma("unroll")                                                          \
    for (int ks = 0; ks < 4; ++ks)                                             \
        bf_[nt][ks] = *(const i32x4*)&pk[(G) & 3][(nt * 32 + l31) * 128        \
                        + ((ks * 32 + lhi * 16) ^ ((l31 & 7) << 4))];          \
    const float sg0_ = sgl[(G) * 64 + l31];                                    \
    const float sg1_ = sgl[(G) * 64 + 32 + l31];                               \
    /* 4: MFMA + per-group fp32 fold */                                        \
    __builtin_amdgcn_s_setprio(1);                                             \
    _Pragma("unroll")                                                          \
    for (int nt = 0; nt < 2; ++nt) {                                           \
        const float sgv_ = nt ? sg1_ : sg0_;                                   \
        _Pragma("unroll")                                                      \
        for (int ms = 0; ms < 2; ++ms) {                                       \
            i32x16 ia = {0,0,0,0,0,0,0,0,0,0,0,0,0,0,0,0};                     \
            _Pragma("unroll")                                                  \
            for (int ks = 0; ks < 4; ++ks)                                     \
                ia = __builtin_amdgcn_mfma_i32_32x32x32_i8(ACUR[ms][ks],       \
                                                    bf_[nt][ks], ia, 0, 0, 0); \
            _Pragma("unroll")                                                  \
            for (int r = 0; r < 16; ++r)                                       \
                facc[ms][nt][r] += sgv_ * (float)ia[r];                        \
        }                                                                      \
    }                                                                          \
    __builtin_amdgcn_s_setprio(0);                                             \
    /* 5: counted drain: only DMA(G+1) must be resident for next body */       \
    __builtin_amdgcn_sched_barrier(0);                                         \
    asm volatile("s_waitcnt vmcnt(12)" ::: "memory");                          \
    __builtin_amdgcn_sched_barrier(0);                                         \
    __builtin_amdgcn_s_barrier();                                              \
    __builtin_amdgcn_sched_barrier(0);                                         \
} while (0)

__global__ __launch_bounds__(256, 3) void w4a8_gemm(
    const uint8_t* __restrict__ qA, const float* __restrict__ s1,
    const uint8_t* __restrict__ w8, const float* __restrict__ sgrp,
    const float* __restrict__ schan, const float* __restrict__ bias,
    float* __restrict__ out)
{
    __shared__ uint8_t pk[4][8192];      // 32 KB: 4-deep B ring
    __shared__ float   sgl[NGRP * BN];   // 16 KB staged group scales

    const int tid   = threadIdx.x;
    const int lane  = tid & 63;
    const int wv    = tid >> 6;          // wave 0..3 -> rows [wv*64, wv*64+64)
    const int l31   = lane & 31;
    const int lhi   = lane >> 5;

    // XCD-aware map: bid -> (ntile, mh) so an ntile's two m-halves sit on the
    // same XCD (blocks dispatched round-robin over 8 XCDs by bid).
    const int bid   = blockIdx.x;        // 0..447
    const int xcd   = bid & 7;
    const int idx   = bid >> 3;          // 0..55
    const int ntile = xcd * 28 + (idx % 28);
    const int mh    = idx / 28;          // m-half 0/1
    const int n0    = ntile * BN;
    const int tile0 = mh * 8 + 2 * wv;   // first 32-row qA tile of this wave

    const uint8_t* abase = qA + l31 * 32 + lhi * 16;

    float facc[2][2][16];
#pragma unroll
    for (int a = 0; a < 2; ++a)
#pragma unroll
    for (int b = 0; b < 2; ++b)
#pragma unroll
    for (int r = 0; r < 16; ++r) facc[a][b][r] = 0.0f;

    // ---- prologue ----
#pragma unroll
    for (int j = 0; j < 16; ++j) {       // stage s_group for our 64 columns
        const int idx2 = tid + j * 256;  // idx2 = g*64 + c
        sgl[idx2] = sgrp[(size_t)(idx2 >> 6) * N_DIM + n0 + (idx2 & 63)];
    }

    i32x4 aA[2][4], aB[2][4];
#pragma unroll
    for (int ms = 0; ms < 2; ++ms)
#pragma unroll
    for (int ks = 0; ks < 4; ++ks)
        aA[ms][ks] = *(const i32x4*)(abase
            + (size_t)((tile0 + ms) * 4 + ks) * 1024);

    __builtin_amdgcn_sched_barrier(0);
    DMA_PK(0, 0);
    DMA_PK(1, 1);
    DMA_PK(2, 2);
    __builtin_amdgcn_sched_barrier(0);
    asm volatile("s_waitcnt vmcnt(4)" ::: "memory");   // DMA(0) resident
    __builtin_amdgcn_sched_barrier(0);
    asm volatile("s_waitcnt lgkmcnt(0)" ::: "memory"); // sgl writes done
    __builtin_amdgcn_s_barrier();
    __builtin_amdgcn_sched_barrier(0);

    // ---- main loop: ping-pong A-fragment registers ----
#pragma unroll 1
    for (int g = 0; g < NGRP; g += 2) {
        BODY(g,     aA, aB);
        BODY(g + 1, aB, aA);
    }

    // ---- epilogue: D = facc * s1[m] * s_channel[n] + bias[n] ----
#pragma unroll
    for (int nt = 0; nt < 2; ++nt) {
        const int col = n0 + nt * 32 + l31;
        const float sch = schan[col];
        const float bv  = bias[col];
#pragma unroll
        for (int ms = 0; ms < 2; ++ms) {
            const int rbase = mh * 256 + wv * 64 + ms * 32 + 4 * lhi;
#pragma unroll
            for (int r = 0; r < 16; ++r) {
                const int row = rbase + (r & 3) + 8 * (r >> 2);
                out[(size_t)row * N_DIM + col] = facc[ms][nt][r] * s1[row] * sch + bv;
            }
        }
    }
}

extern "C" void kernel_launch(void* const* d_in, const int* in_sizes, int n_in,
                              void* d_out, int out_size, void* d_ws, size_t ws_size,
                              hipStream_t stream)
{
    const float* A     = (const float*)d_in[0];
    const int*   w4    = (const int*)  d_in[1];
    const float* sgrp  = (const float*)d_in[2];
    const float* schan = (const float*)d_in[3];
    const float* bias  = (const float*)d_in[4];
    float* out = (float*)d_out;

    // workspace: s1[512] @0, qA (4 MB, fragment-native) @4096,
    //            w8 (112 MB, GEMM-native tiles, [g][ntile]) @4096+4MB
    float*   s1 = (float*)d_ws;
    uint8_t* qA = (uint8_t*)d_ws + 4096;
    uint8_t* w8 = (uint8_t*)d_ws + 4096 + (size_t)M_DIM * K_DIM;

    quant_rows<<<dim3(M_DIM), dim3(256), 0, stream>>>(A, qA, s1);
    repack_w4<<<dim3(56, 64), dim3(256), 0, stream>>>(w4, w8);
    w4a8_gemm<<<dim3(448), dim3(256), 0, stream>>>(qA, s1, w8, sgrp, schan, bias, out);
}

// Round 9
// 774.202 us; speedup vs baseline: 1.0003x; 1.0003x over previous
//
#include <hip/hip_runtime.h>
#include <stdint.h>

#define M_DIM 512
#define K_DIM 8192
#define N_DIM 14336
#define NGRP  64      // K / 128 groups
#define BN    64      // N columns per GEMM workgroup
#define NTILE (N_DIM / BN)   // 224

typedef int   i32x4  __attribute__((ext_vector_type(4)));
typedef int   i32x16 __attribute__((ext_vector_type(16)));
typedef float f32x4  __attribute__((ext_vector_type(4)));

// ---------------- Kernel 1: per-row dynamic int8 quantization ----------------
// Writes qA in MFMA-fragment-native layout:
//   qA[((g*16 + tile)*4 + ks)*1024 + l31*32 + lhi*16 + b]
// where row = tile*32 + l31, k = g*128 + ks*32 + lhi*16 + b.
__global__ __launch_bounds__(256) void quant_rows(const float* __restrict__ A,
                                                  uint8_t* __restrict__ qA,
                                                  float* __restrict__ s1)
{
    const int row  = blockIdx.x;
    const int tid  = threadIdx.x;
    const int tile = row >> 5;
    const int l31  = row & 31;
    const f32x4* src = (const f32x4*)(A + (size_t)row * K_DIM) + tid;

    f32x4 v[8];
#pragma unroll
    for (int i = 0; i < 8; ++i) v[i] = src[i * 256];

    float m = 0.0f;
#pragma unroll
    for (int i = 0; i < 8; ++i)
        m = fmaxf(m, fmaxf(fmaxf(fabsf(v[i].x), fabsf(v[i].y)),
                           fmaxf(fabsf(v[i].z), fabsf(v[i].w))));
#pragma unroll
    for (int off = 32; off > 0; off >>= 1)
        m = fmaxf(m, __shfl_xor(m, off));

    __shared__ float wmax[4];
    if ((tid & 63) == 0) wmax[tid >> 6] = m;
    __syncthreads();
    const float gm = fmaxf(fmaxf(wmax[0], wmax[1]), fmaxf(wmax[2], wmax[3]));
    const float s = gm / 127.0f;   // exact fp32 division, matches reference
    if (tid == 0) s1[row] = s;

#pragma unroll
    for (int i = 0; i < 8; ++i) {
        const int k0  = 4 * (tid + 256 * i);
        const int g   = k0 >> 7;
        const int ks  = (k0 >> 5) & 3;
        const int lhi = (k0 >> 4) & 1;
        const int b   = k0 & 15;
        uint32_t p = 0;
#pragma unroll
        for (int j = 0; j < 4; ++j) {
            float q = rintf(v[i][j] / s);             // round-half-even = np.round
            q = fminf(fmaxf(q, -128.0f), 127.0f);
            p |= ((uint32_t)(uint8_t)(int8_t)(int)q) << (8 * j);
        }
        *(uint32_t*)(qA + (size_t)(g * 16 + tile) * 4096 + ks * 1024
                        + l31 * 32 + lhi * 16 + b) = p;
    }
}

// ---------------- Kernel 2: w4 int32 -> int8 GEMM-native repack (v2) --------
// Block covers 128 k-rows x 256 cols (1 KB contiguous per row -> DRAM page
// locality). Grid (56 nblk, 64 g), x fastest => concurrent blocks stream whole
// 57 KB k-rows collectively. Output tiles indexed [g][ntile] so writes are
// dispatch-contiguous too. Tile image (8 KB per (g,ntile)):
//   byte(col,k) = col*128 + (k ^ ((col&7)<<4)), value = w4[k][n]-8 as int8.
__global__ __launch_bounds__(256) void repack_w4(const int* __restrict__ w4,
                                                 uint8_t* __restrict__ w8)
{
    const int nblk = blockIdx.x;         // 0..55  (256-col slab)
    const int g    = blockIdx.y;         // 0..63
    const int t    = threadIdx.x;
    const int c4   = t & 63;             // col-quad within 256-col slab
    const int kr   = t >> 6;             // 0..3: 32-row k-chunk

    const int colg   = nblk * 256 + c4 * 4;           // global first col
    const int ntile  = colg >> 6;                     // output tile
    const int colt   = colg & 63;                     // col within tile
    uint8_t* dst = w8 + ((size_t)g * NTILE + ntile) * 8192;

#pragma unroll
    for (int sub = 0; sub < 4; ++sub) {
        const int krow = kr * 32 + sub * 8;           // k within group
        const int* src = w4 + (size_t)(g * 128 + krow) * N_DIM + colg;
        i32x4 r[8];
#pragma unroll
        for (int j = 0; j < 8; ++j)
            r[j] = *(const i32x4*)(src + (size_t)j * N_DIM);
#pragma unroll
        for (int c = 0; c < 4; ++c) {
            const int col = colt + c;
            uint32_t lo = ((uint32_t)(r[0][c] - 8) & 0xFFu)
                        | (((uint32_t)(r[1][c] - 8) & 0xFFu) << 8)
                        | (((uint32_t)(r[2][c] - 8) & 0xFFu) << 16)
                        | (((uint32_t)(r[3][c] - 8) & 0xFFu) << 24);
            uint32_t hi = ((uint32_t)(r[4][c] - 8) & 0xFFu)
                        | (((uint32_t)(r[5][c] - 8) & 0xFFu) << 8)
                        | (((uint32_t)(r[6][c] - 8) & 0xFFu) << 16)
                        | (((uint32_t)(r[7][c] - 8) & 0xFFu) << 24);
            // krow is 8-aligned; swz only touches bits 4..6 -> stays 8-aligned
            uint2 v = make_uint2(lo, hi);
            *(uint2*)&dst[col * 128 + (krow ^ ((col & 7) << 4))] = v;
        }
    }
}

// ---------------- Kernel 3: lean W8A8 GEMM ----------------
// BM=256 (4 waves), BN=64. 3 WGs/CU (LDS 48 KB, VGPR<=168). B staged by
// verbatim 8 KB DMA of the pre-swizzled w8 tile into a 4-deep LDS ring
// (depth-3 prefetch); qA fragments prefetched 1 group ahead into registers;
// s_group staged in LDS once. ONE barrier per group; counted vmcnt(12)
// keeps DMA(G+2..3) + qA(G+1) in flight across the barrier. XCD-aware block
// map co-locates an ntile's two m-halves on one XCD (w8 2nd read = L2 hit).

#define DMA_PK(BUF, G) do {                                                    \
    const uint8_t* s0_ = w8 + ((size_t)(G) * NTILE + ntile) * 8192             \
                         + wv * 1024 + lane * 16;                              \
    __builtin_amdgcn_global_load_lds(                                          \
        (const __attribute__((address_space(1))) void*)s0_,                    \
        (__attribute__((address_space(3))) void*)&pk[BUF][wv * 1024], 16, 0, 0);\
    __builtin_amdgcn_global_load_lds(                                          \
        (const __attribute__((address_space(1))) void*)(s0_ + 4096),           \
        (__attribute__((address_space(3))) void*)&pk[BUF][wv * 1024 + 4096],   \
        16, 0, 0);                                                             \
} while (0)

#define BODY(G, ACUR, ANXT) do {                                               \
    /* 1: prefetch A fragments for G+1 */                                      \
    { const int gn_ = ((G) + 1 < NGRP) ? (G) + 1 : NGRP - 1;                   \
      _Pragma("unroll")                                                        \
      for (int ms = 0; ms < 2; ++ms)                                           \
      _Pragma("unroll")                                                        \
      for (int ks = 0; ks < 4; ++ks)                                           \
          ANXT[ms][ks] = *(const i32x4*)(abase                                 \
              + (size_t)((gn_ * 16 + tile0 + ms) * 4 + ks) * 1024); }          \
    /* 2: issue DMA for G+3 */                                                 \
    { const int gd_ = ((G) + 3 < NGRP) ? (G) + 3 : NGRP - 1;                   \
      DMA_PK(((G) + 3) & 3, gd_); }                                            \
    /* 3: B fragments from pk[G&3] + group scales from LDS */                  \
    i32x4 bf_[2][4];                                                           \
    _Pragma("unroll")                                                          \
    for (int nt = 0; nt < 2; ++nt)                                             \
    _Pragma("unroll")                                                          \
    for (int ks = 0; ks < 4; ++ks)                                             \
        bf_[nt][ks] = *(const i32x4*)&pk[(G) & 3][(nt * 32 + l31) * 128        \
                        + ((ks * 32 + lhi * 16) ^ ((l31 & 7) << 4))];          \
    const float sg0_ = sgl[(G) * 64 + l31];                                    \
    const float sg1_ = sgl[(G) * 64 + 32 + l31];                               \
    /* 4: MFMA + per-group fp32 fold */                                        \
    __builtin_amdgcn_s_setprio(1);                                             \
    _Pragma("unroll")                                                          \
    for (int nt = 0; nt < 2; ++nt) {                                           \
        const float sgv_ = nt ? sg1_ : sg0_;                                   \
        _Pragma("unroll")                                                      \
        for (int ms = 0; ms < 2; ++ms) {                                       \
            i32x16 ia = {0,0,0,0,0,0,0,0,0,0,0,0,0,0,0,0};                     \
            _Pragma("unroll")                                                  \
            for (int ks = 0; ks < 4; ++ks)                                     \
                ia = __builtin_amdgcn_mfma_i32_32x32x32_i8(ACUR[ms][ks],       \
                                                    bf_[nt][ks], ia, 0, 0, 0); \
            _Pragma("unroll")                                                  \
            for (int r = 0; r < 16; ++r)                                       \
                facc[ms][nt][r] += sgv_ * (float)ia[r];                        \
        }                                                                      \
    }                                                                          \
    __builtin_amdgcn_s_setprio(0);                                             \
    /* 5: counted drain: only DMA(G+1) must be resident for next body */       \
    __builtin_amdgcn_sched_barrier(0);                                         \
    asm volatile("s_waitcnt vmcnt(12)" ::: "memory");                          \
    __builtin_amdgcn_sched_barrier(0);                                         \
    __builtin_amdgcn_s_barrier();                                              \
    __builtin_amdgcn_sched_barrier(0);                                         \
} while (0)

__global__ __launch_bounds__(256, 3) void w4a8_gemm(
    const uint8_t* __restrict__ qA, const float* __restrict__ s1,
    const uint8_t* __restrict__ w8, const float* __restrict__ sgrp,
    const float* __restrict__ schan, const float* __restrict__ bias,
    float* __restrict__ out)
{
    __shared__ uint8_t pk[4][8192];      // 32 KB: 4-deep B ring
    __shared__ float   sgl[NGRP * BN];   // 16 KB staged group scales

    const int tid   = threadIdx.x;
    const int lane  = tid & 63;
    const int wv    = tid >> 6;          // wave 0..3 -> rows [wv*64, wv*64+64)
    const int l31   = lane & 31;
    const int lhi   = lane >> 5;

    // XCD-aware map: bid -> (ntile, mh) so an ntile's two m-halves sit on the
    // same XCD (blocks dispatched round-robin over 8 XCDs by bid).
    const int bid   = blockIdx.x;        // 0..447
    const int xcd   = bid & 7;
    const int idx   = bid >> 3;          // 0..55
    const int ntile = xcd * 28 + (idx % 28);
    const int mh    = idx / 28;          // m-half 0/1
    const int n0    = ntile * BN;
    const int tile0 = mh * 8 + 2 * wv;   // first 32-row qA tile of this wave

    const uint8_t* abase = qA + l31 * 32 + lhi * 16;

    float facc[2][2][16];
#pragma unroll
    for (int a = 0; a < 2; ++a)
#pragma unroll
    for (int b = 0; b < 2; ++b)
#pragma unroll
    for (int r = 0; r < 16; ++r) facc[a][b][r] = 0.0f;

    // ---- prologue ----
#pragma unroll
    for (int j = 0; j < 16; ++j) {       // stage s_group for our 64 columns
        const int idx2 = tid + j * 256;  // idx2 = g*64 + c
        sgl[idx2] = sgrp[(size_t)(idx2 >> 6) * N_DIM + n0 + (idx2 & 63)];
    }

    i32x4 aA[2][4], aB[2][4];
#pragma unroll
    for (int ms = 0; ms < 2; ++ms)
#pragma unroll
    for (int ks = 0; ks < 4; ++ks)
        aA[ms][ks] = *(const i32x4*)(abase
            + (size_t)((tile0 + ms) * 4 + ks) * 1024);

    __builtin_amdgcn_sched_barrier(0);
    DMA_PK(0, 0);
    DMA_PK(1, 1);
    DMA_PK(2, 2);
    __builtin_amdgcn_sched_barrier(0);
    asm volatile("s_waitcnt vmcnt(4)" ::: "memory");   // DMA(0) resident
    __builtin_amdgcn_sched_barrier(0);
    asm volatile("s_waitcnt lgkmcnt(0)" ::: "memory"); // sgl writes done
    __builtin_amdgcn_s_barrier();
    __builtin_amdgcn_sched_barrier(0);

    // ---- main loop: ping-pong A-fragment registers ----
#pragma unroll 1
    for (int g = 0; g < NGRP; g += 2) {
        BODY(g,     aA, aB);
        BODY(g + 1, aB, aA);
    }

    // ---- epilogue: D = facc * s1[m] * s_channel[n] + bias[n] ----
#pragma unroll
    for (int nt = 0; nt < 2; ++nt) {
        const int col = n0 + nt * 32 + l31;
        const float sch = schan[col];
        const float bv  = bias[col];
#pragma unroll
        for (int ms = 0; ms < 2; ++ms) {
            const int rbase = mh * 256 + wv * 64 + ms * 32 + 4 * lhi;
#pragma unroll
            for (int r = 0; r < 16; ++r) {
                const int row = rbase + (r & 3) + 8 * (r >> 2);
                out[(size_t)row * N_DIM + col] = facc[ms][nt][r] * s1[row] * sch + bv;
            }
        }
    }
}

extern "C" void kernel_launch(void* const* d_in, const int* in_sizes, int n_in,
                              void* d_out, int out_size, void* d_ws, size_t ws_size,
                              hipStream_t stream)
{
    const float* A     = (const float*)d_in[0];
    const int*   w4    = (const int*)  d_in[1];
    const float* sgrp  = (const float*)d_in[2];
    const float* schan = (const float*)d_in[3];
    const float* bias  = (const float*)d_in[4];
    float* out = (float*)d_out;

    // workspace: s1[512] @0, qA (4 MB, fragment-native) @4096,
    //            w8 (112 MB, GEMM-native tiles, [g][ntile]) @4096+4MB
    float*   s1 = (float*)d_ws;
    uint8_t* qA = (uint8_t*)d_ws + 4096;
    uint8_t* w8 = (uint8_t*)d_ws + 4096 + (size_t)M_DIM * K_DIM;

    quant_rows<<<dim3(M_DIM), dim3(256), 0, stream>>>(A, qA, s1);
    repack_w4<<<dim3(56, 64), dim3(256), 0, stream>>>(w4, w8);
    w4a8_gemm<<<dim3(448), dim3(256), 0, stream>>>(qA, s1, w8, sgrp, schan, bias, out);
}

// Round 10
// 572.723 us; speedup vs baseline: 1.3522x; 1.3518x over previous
//
#include <hip/hip_runtime.h>
#include <stdint.h>

#define M_DIM 512
#define K_DIM 8192
#define N_DIM 14336
#define NGRP  64      // K / 128 groups
#define BN    64      // N columns per workgroup

typedef int   i32x4  __attribute__((ext_vector_type(4)));
typedef int   i32x16 __attribute__((ext_vector_type(16)));
typedef float f32x4  __attribute__((ext_vector_type(4)));

// ---------------- Kernel 1: per-row dynamic int8 quantization ----------------
// Writes qA in MFMA-fragment-native layout:
//   qA[((g*16 + tile)*4 + ks)*1024 + l31*32 + lhi*16 + b]
// where row = tile*32 + l31, k = g*128 + ks*32 + lhi*16 + b.
__global__ __launch_bounds__(256) void quant_rows(const float* __restrict__ A,
                                                  uint8_t* __restrict__ qA,
                                                  float* __restrict__ s1)
{
    const int row  = blockIdx.x;
    const int tid  = threadIdx.x;
    const int tile = row >> 5;
    const int l31  = row & 31;
    const f32x4* src = (const f32x4*)(A + (size_t)row * K_DIM) + tid;

    f32x4 v[8];
#pragma unroll
    for (int i = 0; i < 8; ++i) v[i] = src[i * 256];

    float m = 0.0f;
#pragma unroll
    for (int i = 0; i < 8; ++i)
        m = fmaxf(m, fmaxf(fmaxf(fabsf(v[i].x), fabsf(v[i].y)),
                           fmaxf(fabsf(v[i].z), fabsf(v[i].w))));
#pragma unroll
    for (int off = 32; off > 0; off >>= 1)
        m = fmaxf(m, __shfl_xor(m, off));

    __shared__ float wmax[4];
    if ((tid & 63) == 0) wmax[tid >> 6] = m;
    __syncthreads();
    const float gm = fmaxf(fmaxf(wmax[0], wmax[1]), fmaxf(wmax[2], wmax[3]));
    const float s = gm / 127.0f;   // exact fp32 division, matches reference
    if (tid == 0) s1[row] = s;

#pragma unroll
    for (int i = 0; i < 8; ++i) {
        const int k0  = 4 * (tid + 256 * i);
        const int g   = k0 >> 7;
        const int ks  = (k0 >> 5) & 3;
        const int lhi = (k0 >> 4) & 1;
        const int b   = k0 & 15;
        uint32_t p = 0;
#pragma unroll
        for (int j = 0; j < 4; ++j) {
            float q = rintf(v[i][j] / s);             // round-half-even = np.round
            q = fminf(fmaxf(q, -128.0f), 127.0f);
            p |= ((uint32_t)(uint8_t)(int8_t)(int)q) << (8 * j);
        }
        *(uint32_t*)(qA + (size_t)(g * 16 + tile) * 4096 + ks * 1024
                        + l31 * 32 + lhi * 16 + b) = p;
    }
}

// ---------------- Kernel 2: fused W4A8 GEMM ----------------
// BM=256 (4 waves, 256 thr), BN=64, grid 448, 80 KB LDS -> 2 WGs/CU.
// w4 DMA'd raw (int32 [128k][64n], 32 KB) into a depth-2 ring; per group the
// WG packs raw -> int8 col-major XOR-swizzled pk (double-buffered); MFMA from
// pk + register A-frags (depth-1 prefetch). Counted vmcnt(18) drains only
// DMA(G+1); DMA(G+2) + qA(G+1) + sg(G+1) stay in flight across both barriers.

#define DMA_RAW(SLOT, G) do {                                                  \
    _Pragma("unroll")                                                          \
    for (int j_ = 0; j_ < 8; ++j_) {                                           \
        const int ci_ = j_ * 256 + tid;   /* 16B chunk: k=ci>>4, colq=ci&15 */ \
        const int* gsrc_ = w4 + (size_t)((G) * 128 + (ci_ >> 4)) * N_DIM       \
                           + n0 + (ci_ & 15) * 4;                              \
        __builtin_amdgcn_global_load_lds(                                      \
            (const __attribute__((address_space(1))) void*)gsrc_,              \
            (__attribute__((address_space(3))) void*)                          \
                &raw[SLOT][(j_ * 256 + wv * 64) * 4],                          \
            16, 0, 0);                                                         \
    }                                                                          \
} while (0)

// raw[RSLOT] (int32 [k][64]) -> pk[PBUF] (int8 col-major [64][128], swizzled)
#define PACK_GROUP(PBUF, RSLOT) do {                                           \
    _Pragma("unroll")                                                          \
    for (int q_ = 0; q_ < 2; ++q_) {                                           \
        const int kq_ = (tid >> 4) + q_ * 16;                                  \
        i32x4 r_[4];                                                           \
        _Pragma("unroll")                                                      \
        for (int j_ = 0; j_ < 4; ++j_)                                         \
            r_[j_] = *(const i32x4*)&raw[RSLOT][(kq_ * 4 + j_) * 64 + c4 * 4]; \
        _Pragma("unroll")                                                      \
        for (int c_ = 0; c_ < 4; ++c_) {                                       \
            const int col_ = c4 * 4 + c_;                                      \
            uint32_t d_ = ((uint32_t)(r_[0][c_] - 8) & 0xFFu)                  \
                        | (((uint32_t)(r_[1][c_] - 8) & 0xFFu) << 8)           \
                        | (((uint32_t)(r_[2][c_] - 8) & 0xFFu) << 16)          \
                        | (((uint32_t)(r_[3][c_] - 8) & 0xFFu) << 24);         \
            *(uint32_t*)&pk[PBUF][col_ * 128                                   \
                + ((kq_ * 4) ^ ((col_ & 7) << 4))] = d_;                       \
        }                                                                      \
    }                                                                          \
} while (0)

#define BODY(G, ACUR, ANXT, SGC, SGN) do {                                     \
    /* 1: DMA(G+2) into raw[G&1] (slot's old group packed last body) */        \
    DMA_RAW((G) & 1, ((G) + 2 < NGRP) ? (G) + 2 : NGRP - 1);                   \
    /* 2: prefetch A fragments + group scales for G+1 */                       \
    { const int gn_ = ((G) + 1 < NGRP) ? (G) + 1 : NGRP - 1;                   \
      _Pragma("unroll")                                                        \
      for (int ms = 0; ms < 2; ++ms)                                           \
      _Pragma("unroll")                                                        \
      for (int ks = 0; ks < 4; ++ks)                                           \
          ANXT[ms][ks] = *(const i32x4*)(abase                                 \
              + (size_t)((gn_ * 16 + tile0 + ms) * 4 + ks) * 1024);            \
      SGN[0] = sgrp[(size_t)gn_ * N_DIM + n0 + l31];                           \
      SGN[1] = sgrp[(size_t)gn_ * N_DIM + n0 + 32 + l31]; }                    \
    /* 3: B fragments from pk[G&1] */                                          \
    i32x4 bf_[2][4];                                                           \
    _Pragma("unroll")                                                          \
    for (int nt = 0; nt < 2; ++nt)                                             \
    _Pragma("unroll")                                                          \
    for (int ks = 0; ks < 4; ++ks)                                             \
        bf_[nt][ks] = *(const i32x4*)&pk[(G) & 1][(nt * 32 + l31) * 128        \
                        + ((ks * 32 + lhi * 16) ^ ((l31 & 7) << 4))];          \
    /* 4: MFMA + per-group fp32 fold */                                        \
    __builtin_amdgcn_s_setprio(1);                                             \
    _Pragma("unroll")                                                          \
    for (int nt = 0; nt < 2; ++nt) {                                           \
        const float sgv_ = SGC[nt];                                            \
        _Pragma("unroll")                                                      \
        for (int ms = 0; ms < 2; ++ms) {                                       \
            i32x16 ia = {0,0,0,0,0,0,0,0,0,0,0,0,0,0,0,0};                     \
            _Pragma("unroll")                                                  \
            for (int ks = 0; ks < 4; ++ks)                                     \
                ia = __builtin_amdgcn_mfma_i32_32x32x32_i8(ACUR[ms][ks],       \
                                                    bf_[nt][ks], ia, 0, 0, 0); \
            _Pragma("unroll")                                                  \
            for (int r = 0; r < 16; ++r)                                       \
                facc[ms][nt][r] += sgv_ * (float)ia[r];                        \
        }                                                                      \
    }                                                                          \
    __builtin_amdgcn_s_setprio(0);                                             \
    /* 5: drain DMA(G+1) only; keep DMA(G+2)+A(G+1)+sg(G+1) in flight */       \
    __builtin_amdgcn_sched_barrier(0);                                         \
    asm volatile("s_waitcnt vmcnt(18)" ::: "memory");                          \
    __builtin_amdgcn_sched_barrier(0);                                         \
    __builtin_amdgcn_s_barrier();                                              \
    __builtin_amdgcn_sched_barrier(0);                                         \
    /* 6: pack group G+1 from raw[(G+1)&1] into pk[(G+1)&1] */                 \
    PACK_GROUP(((G) + 1) & 1, ((G) + 1) & 1);                                  \
    /* 7: pack visible to all waves */                                         \
    asm volatile("s_waitcnt lgkmcnt(0)" ::: "memory");                         \
    __builtin_amdgcn_s_barrier();                                              \
    __builtin_amdgcn_sched_barrier(0);                                         \
} while (0)

__global__ __launch_bounds__(256, 2) void w4a8_gemm(
    const uint8_t* __restrict__ qA, const float* __restrict__ s1,
    const int* __restrict__ w4, const float* __restrict__ sgrp,
    const float* __restrict__ schan, const float* __restrict__ bias,
    float* __restrict__ out)
{
    __shared__ int     raw[2][128 * 64];   // 64 KB: depth-2 raw w4 ring
    __shared__ uint8_t pk[2][8192];        // 16 KB: packed int8 double buffer

    const int tid  = threadIdx.x;
    const int lane = tid & 63;
    const int wv   = tid >> 6;            // wave 0..3
    const int l31  = lane & 31;
    const int lhi  = lane >> 5;
    const int c4   = tid & 15;            // pack: column quad

    // XCD map: the two m-halves of an ntile sit adjacent on the same XCD
    // (blocks round-robin XCDs by blockIdx). bid = xcd + 8*(2*j + mh).
    const int bid   = blockIdx.x;         // 0..447
    const int xcd   = bid & 7;
    const int idx   = bid >> 3;           // 0..55
    const int ntile = xcd * 28 + (idx >> 1);
    const int mh    = idx & 1;            // m-half 0/1
    const int n0    = ntile * BN;
    const int tile0 = mh * 8 + 2 * wv;    // first 32-row qA tile of this wave

    const uint8_t* abase = qA + l31 * 32 + lhi * 16;

    float facc[2][2][16];
#pragma unroll
    for (int a = 0; a < 2; ++a)
#pragma unroll
    for (int b = 0; b < 2; ++b)
#pragma unroll
    for (int r = 0; r < 16; ++r) facc[a][b][r] = 0.0f;

    // ---- prologue: DMA g0,g1; A(g0)+sg(g0) regs; pack g0 ----
    DMA_RAW(0, 0);
    DMA_RAW(1, 1);

    i32x4 aA[2][4], aB[2][4];
    float sgA[2], sgB[2];
#pragma unroll
    for (int ms = 0; ms < 2; ++ms)
#pragma unroll
    for (int ks = 0; ks < 4; ++ks)
        aA[ms][ks] = *(const i32x4*)(abase
            + (size_t)((tile0 + ms) * 4 + ks) * 1024);
    sgA[0] = sgrp[n0 + l31];
    sgA[1] = sgrp[n0 + 32 + l31];

    __builtin_amdgcn_sched_barrier(0);
    asm volatile("s_waitcnt vmcnt(18)" ::: "memory");  // drain DMA(g0) only
    __builtin_amdgcn_sched_barrier(0);
    __builtin_amdgcn_s_barrier();
    __builtin_amdgcn_sched_barrier(0);
    PACK_GROUP(0, 0);
    asm volatile("s_waitcnt lgkmcnt(0)" ::: "memory");
    __builtin_amdgcn_s_barrier();
    __builtin_amdgcn_sched_barrier(0);

    // ---- main loop: ping-pong A-frag / scale registers ----
#pragma unroll 1
    for (int g = 0; g < NGRP; g += 2) {
        BODY(g,     aA, aB, sgA, sgB);
        BODY(g + 1, aB, aA, sgB, sgA);
    }

    // ---- epilogue: D = facc * s1[m] * s_channel[n] + bias[n] ----
#pragma unroll
    for (int nt = 0; nt < 2; ++nt) {
        const int col = n0 + nt * 32 + l31;
        const float sch = schan[col];
        const float bv  = bias[col];
#pragma unroll
        for (int ms = 0; ms < 2; ++ms) {
            const int rbase = mh * 256 + wv * 64 + ms * 32 + 4 * lhi;
#pragma unroll
            for (int r = 0; r < 16; ++r) {
                const int row = rbase + (r & 3) + 8 * (r >> 2);
                out[(size_t)row * N_DIM + col] = facc[ms][nt][r] * s1[row] * sch + bv;
            }
        }
    }
}

extern "C" void kernel_launch(void* const* d_in, const int* in_sizes, int n_in,
                              void* d_out, int out_size, void* d_ws, size_t ws_size,
                              hipStream_t stream)
{
    const float* A     = (const float*)d_in[0];
    const int*   w4    = (const int*)  d_in[1];
    const float* sgrp  = (const float*)d_in[2];
    const float* schan = (const float*)d_in[3];
    const float* bias  = (const float*)d_in[4];
    float* out = (float*)d_out;

    // workspace: s1[512] @0, qA (4 MB, fragment-native) @4096
    float*   s1 = (float*)d_ws;
    uint8_t* qA = (uint8_t*)d_ws + 4096;

    quant_rows<<<dim3(M_DIM), dim3(256), 0, stream>>>(A, qA, s1);
    w4a8_gemm<<<dim3(448), dim3(256), 0, stream>>>(qA, s1, w4, sgrp, schan, bias, out);
}

// Round 11
// 203.091 us; speedup vs baseline: 3.8131x; 2.8200x over previous
//
#include <hip/hip_runtime.h>
#include <stdint.h>

#define M_DIM 512
#define K_DIM 8192
#define N_DIM 14336
#define NGRP  64      // K / 128 groups
#define BN    64      // N columns per workgroup

typedef int   i32x4  __attribute__((ext_vector_type(4)));
typedef int   i32x16 __attribute__((ext_vector_type(16)));
typedef float f32x4  __attribute__((ext_vector_type(4)));

// ---------------- Kernel 1: per-row dynamic int8 quantization ----------------
// Writes qA in MFMA-fragment-native layout:
//   qA[((g*16 + tile)*4 + ks)*1024 + l31*32 + lhi*16 + b]
// where row = tile*32 + l31, k = g*128 + ks*32 + lhi*16 + b.
__global__ __launch_bounds__(256) void quant_rows(const float* __restrict__ A,
                                                  uint8_t* __restrict__ qA,
                                                  float* __restrict__ s1)
{
    const int row  = blockIdx.x;
    const int tid  = threadIdx.x;
    const int tile = row >> 5;
    const int l31  = row & 31;
    const f32x4* src = (const f32x4*)(A + (size_t)row * K_DIM) + tid;

    f32x4 v[8];
#pragma unroll
    for (int i = 0; i < 8; ++i) v[i] = src[i * 256];

    float m = 0.0f;
#pragma unroll
    for (int i = 0; i < 8; ++i)
        m = fmaxf(m, fmaxf(fmaxf(fabsf(v[i].x), fabsf(v[i].y)),
                           fmaxf(fabsf(v[i].z), fabsf(v[i].w))));
#pragma unroll
    for (int off = 32; off > 0; off >>= 1)
        m = fmaxf(m, __shfl_xor(m, off));

    __shared__ float wmax[4];
    if ((tid & 63) == 0) wmax[tid >> 6] = m;
    __syncthreads();
    const float gm = fmaxf(fmaxf(wmax[0], wmax[1]), fmaxf(wmax[2], wmax[3]));
    const float s = gm / 127.0f;   // exact fp32 division, matches reference
    if (tid == 0) s1[row] = s;

#pragma unroll
    for (int i = 0; i < 8; ++i) {
        const int k0  = 4 * (tid + 256 * i);
        const int g   = k0 >> 7;
        const int ks  = (k0 >> 5) & 3;
        const int lhi = (k0 >> 4) & 1;
        const int b   = k0 & 15;
        uint32_t p = 0;
#pragma unroll
        for (int j = 0; j < 4; ++j) {
            float q = rintf(v[i][j] / s);             // round-half-even = np.round
            q = fminf(fmaxf(q, -128.0f), 127.0f);
            p |= ((uint32_t)(uint8_t)(int8_t)(int)q) << (8 * j);
        }
        *(uint32_t*)(qA + (size_t)(g * 16 + tile) * 4096 + ks * 1024
                        + l31 * 32 + lhi * 16 + b) = p;
    }
}

// ---------------- Kernel 2: fused W4A8 GEMM (R3 champion + issue reorder) ----
// BM=512 (8 waves), BN=64, grid 224, 1 WG/CU. w4 streamed HBM->LDS via
// global_load_lds into a triple-buffered raw ring; per group pack raw ->
// int8 col-major XOR-swizzled pk (double buffer); MFMA from pk + register
// A-frags. KEY ORDERING INVARIANT: A-prefetch(G+1) is issued BEFORE
// DMA(G+2) in every body, so the compiler's in-order vmcnt wait for A(G)
// before the MFMA never drains DMA(G+1) — the DMA stream is decoupled from
// the MFMA pipe and drained exactly once by the explicit vmcnt(12)
// (= A(G+1)x8 + DMA(G+2)x4 left in flight) right before pack.

#define DMA_GROUP(BUF, G) do {                                                 \
    _Pragma("unroll")                                                          \
    for (int j_ = 0; j_ < 4; ++j_) {                                           \
        const int idx_ = j_ * 512 + tid;                                       \
        const int k_   = idx_ >> 4;                                            \
        const int c4_  = idx_ & 15;                                            \
        const int* gsrc_ = w4 + (size_t)((G) * 128 + k_) * N_DIM + n0 + c4_*4; \
        __builtin_amdgcn_global_load_lds(                                      \
            (const __attribute__((address_space(1))) void*)gsrc_,              \
            (__attribute__((address_space(3))) void*)&raw[BUF][(j_*512 + wv*64)*4], \
            16, 0, 0);                                                         \
    }                                                                          \
} while (0)

// pack raw[RBUF] (int32 [k][n]) -> pk[PBUF] (int8 col-major [n][k], swizzled)
#define PACK_GROUP(PBUF, RBUF) do {                                            \
    i32x4 r_[4];                                                               \
    _Pragma("unroll")                                                          \
    for (int j_ = 0; j_ < 4; ++j_)                                             \
        r_[j_] = *(const i32x4*)&raw[RBUF][(kq * 4 + j_) * 64 + c4 * 4];       \
    _Pragma("unroll")                                                          \
    for (int c_ = 0; c_ < 4; ++c_) {                                           \
        const int col_ = c4 * 4 + c_;                                          \
        uint32_t d_ =  ((uint32_t)(r_[0][c_] - 8) & 0xFFu)                     \
                    | (((uint32_t)(r_[1][c_] - 8) & 0xFFu) << 8)               \
                    | (((uint32_t)(r_[2][c_] - 8) & 0xFFu) << 16)              \
                    | (((uint32_t)(r_[3][c_] - 8) & 0xFFu) << 24);             \
        *(uint32_t*)&pk[PBUF][col_ * 128 + ((kq * 4) ^ ((col_ & 7) << 4))] = d_; \
    }                                                                          \
} while (0)

#define BODY(G, RP, WP, ACUR, ANXT) do {                                       \
    /* 1: prefetch A fragments for G+1 — MUST be issued before the DMA so    */\
    /*    the pre-MFMA wait for A(G) (older than DMA(G+1)) stays decoupled.  */\
    { const int gn_ = ((G) + 1 < NGRP) ? (G) + 1 : NGRP - 1;                   \
      _Pragma("unroll")                                                        \
      for (int ms = 0; ms < 2; ++ms)                                           \
      _Pragma("unroll")                                                        \
      for (int ks = 0; ks < 4; ++ks)                                           \
          ANXT[ms][ks] = *(const i32x4*)(abase                                 \
              + (size_t)((gn_ * 16 + 2 * wv + ms) * 4 + ks) * 1024); }         \
    /* 2: issue DMA for G+2 */                                                 \
    { const int gd_ = ((G) + 2 < NGRP) ? (G) + 2 : NGRP - 1;                   \
      DMA_GROUP(((G) + 2) % 3, gd_); }                                         \
    /* 3: B fragments + group scales from LDS */                               \
    i32x4 bf_[2][4];                                                           \
    _Pragma("unroll")                                                          \
    for (int nt = 0; nt < 2; ++nt)                                             \
    _Pragma("unroll")                                                          \
    for (int ks = 0; ks < 4; ++ks)                                             \
        bf_[nt][ks] = *(const i32x4*)&pk[RP][(nt*32 + l31) * 128               \
                        + ((ks*32 + lhi*16) ^ ((l31 & 7) << 4))];              \
    const float sg0_ = sgl[(G) * 64 + l31];                                    \
    const float sg1_ = sgl[(G) * 64 + 32 + l31];                               \
    /* 4: MFMA + per-group fp32 fold */                                        \
    __builtin_amdgcn_s_setprio(1);                                             \
    _Pragma("unroll")                                                          \
    for (int nt = 0; nt < 2; ++nt) {                                           \
        const float sgv_ = nt ? sg1_ : sg0_;                                   \
        _Pragma("unroll")                                                      \
        for (int ms = 0; ms < 2; ++ms) {                                       \
            i32x16 ia = {0,0,0,0,0,0,0,0,0,0,0,0,0,0,0,0};                     \
            _Pragma("unroll")                                                  \
            for (int ks = 0; ks < 4; ++ks)                                     \
                ia = __builtin_amdgcn_mfma_i32_32x32x32_i8(ACUR[ms][ks],       \
                                                    bf_[nt][ks], ia, 0, 0, 0); \
            _Pragma("unroll")                                                  \
            for (int r = 0; r < 16; ++r)                                       \
                facc[ms][nt][r] += sgv_ * (float)ia[r];                        \
        }                                                                      \
    }                                                                          \
    __builtin_amdgcn_s_setprio(0);                                             \
    /* 5: vmcnt(12) pops exactly DMA(G+1); A(G+1)x8 + DMA(G+2)x4 stay live */  \
    __builtin_amdgcn_sched_barrier(0);                                         \
    asm volatile("s_waitcnt vmcnt(12)" ::: "memory");                          \
    __builtin_amdgcn_sched_barrier(0);                                         \
    __builtin_amdgcn_s_barrier();                                              \
    __builtin_amdgcn_sched_barrier(0);                                         \
    /* 6: pack group G+1 */                                                    \
    PACK_GROUP(WP, ((G) + 1) % 3);                                             \
    /* 7: pack visible to all */                                               \
    asm volatile("s_waitcnt lgkmcnt(0)" ::: "memory");                         \
    __builtin_amdgcn_s_barrier();                                              \
    __builtin_amdgcn_sched_barrier(0);                                         \
} while (0)

__global__ __launch_bounds__(512) void w4a8_gemm(
    const uint8_t* __restrict__ qA, const float* __restrict__ s1,
    const int* __restrict__ w4, const float* __restrict__ sgrp,
    const float* __restrict__ schan, const float* __restrict__ bias,
    float* __restrict__ out)
{
    __shared__ int     raw[3][128 * 64];   // 3 x 32 KB raw int32 w4 tiles
    __shared__ uint8_t pk[2][64 * 128];    // 2 x 8 KB packed int8 (col-major)
    __shared__ float   sgl[NGRP * BN];     // 16 KB staged group scales

    const int tid  = threadIdx.x;
    const int lane = tid & 63;
    const int wv   = tid >> 6;        // wave 0..7 -> rows [wv*64, wv*64+64)
    const int l31  = lane & 31;
    const int lhi  = lane >> 5;
    const int n0   = blockIdx.x * BN;
    const int c4   = tid & 15;        // pack: column quad
    const int kq   = tid >> 4;        // pack: k quad (0..31)

    const uint8_t* abase = qA + l31 * 32 + lhi * 16;

    float facc[2][2][16];
#pragma unroll
    for (int a = 0; a < 2; ++a)
#pragma unroll
    for (int b = 0; b < 2; ++b)
#pragma unroll
    for (int r = 0; r < 16; ++r) facc[a][b][r] = 0.0f;

    // ---- prologue (order: sgl loads, A(g0) loads, DMA(0), DMA(1)) ----
#pragma unroll
    for (int j = 0; j < 8; ++j) {
        const int idx = tid + j * 512;              // idx = g*64 + c
        sgl[idx] = sgrp[(size_t)(idx >> 6) * N_DIM + n0 + (idx & 63)];
    }

    i32x4 aA[2][4], aB[2][4];
#pragma unroll
    for (int ms = 0; ms < 2; ++ms)
#pragma unroll
    for (int ks = 0; ks < 4; ++ks)
        aA[ms][ks] = *(const i32x4*)(abase + (size_t)((2 * wv + ms) * 4 + ks) * 1024);

    DMA_GROUP(0, 0);
    DMA_GROUP(1, 1);

    __builtin_amdgcn_sched_barrier(0);
    asm volatile("s_waitcnt vmcnt(4)" ::: "memory");  // drain sgl+aA+DMA(0); keep DMA(1)
    __builtin_amdgcn_sched_barrier(0);
    asm volatile("s_waitcnt lgkmcnt(0)" ::: "memory"); // sgl ds_writes visible
    __builtin_amdgcn_s_barrier();
    __builtin_amdgcn_sched_barrier(0);
    PACK_GROUP(0, 0);
    asm volatile("s_waitcnt lgkmcnt(0)" ::: "memory");
    __builtin_amdgcn_s_barrier();
    __builtin_amdgcn_sched_barrier(0);

    // ---- main loop: ping-pong pk buffers and A-fragment registers ----
#pragma unroll 1
    for (int g = 0; g < NGRP; g += 2) {
        BODY(g,     0, 1, aA, aB);
        BODY(g + 1, 1, 0, aB, aA);
    }

    // ---- epilogue: D = facc * s1[m] * s_channel[n] + bias[n] ----
#pragma unroll
    for (int nt = 0; nt < 2; ++nt) {
        const int col = n0 + nt * 32 + l31;
        const float sch = schan[col];
        const float bv  = bias[col];
#pragma unroll
        for (int ms = 0; ms < 2; ++ms) {
            const int rbase = wv * 64 + ms * 32 + 4 * lhi;
#pragma unroll
            for (int r = 0; r < 16; ++r) {
                const int row = rbase + (r & 3) + 8 * (r >> 2);
                out[(size_t)row * N_DIM + col] = facc[ms][nt][r] * s1[row] * sch + bv;
            }
        }
    }
}

extern "C" void kernel_launch(void* const* d_in, const int* in_sizes, int n_in,
                              void* d_out, int out_size, void* d_ws, size_t ws_size,
                              hipStream_t stream)
{
    const float* A     = (const float*)d_in[0];
    const int*   w4    = (const int*)  d_in[1];
    const float* sgrp  = (const float*)d_in[2];
    const float* schan = (const float*)d_in[3];
    const float* bias  = (const float*)d_in[4];
    float* out = (float*)d_out;

    // workspace: s1[512] @0, qA (4 MB, fragment-native) @4096
    float*   s1 = (float*)d_ws;
    uint8_t* qA = (uint8_t*)d_ws + 4096;

    quant_rows<<<dim3(M_DIM), dim3(256), 0, stream>>>(A, qA, s1);
    w4a8_gemm<<<dim3(N_DIM / BN), dim3(512), 0, stream>>>(qA, s1, w4, sgrp, schan, bias, out);
}